// Round 2
// baseline (1099.534 us; speedup 1.0000x reference)
//
#include <hip/hip_runtime.h>

#define DIM 64

// One 64-lane wave per edge (grid-stride over edges).
// lane l handles embedding dim l: out[dst][l] += w * in[src][l]
__global__ void spmm_scatter(const float* __restrict__ xin,
                             const int* __restrict__ esrc,
                             const int* __restrict__ edst,
                             const float* __restrict__ ew,
                             float* __restrict__ xout,
                             int num_edges) {
    const int lane   = threadIdx.x & 63;
    const int wave   = (int)((blockIdx.x * blockDim.x + threadIdx.x) >> 6);
    const int nwaves = (int)((gridDim.x * blockDim.x) >> 6);

    for (int e = wave; e < num_edges; e += nwaves) {
        const int   s = esrc[e];
        const int   d = edst[e];
        const float w = ew[e];
        const float v = w * xin[(size_t)s * DIM + lane];
        atomicAdd(&xout[(size_t)d * DIM + lane], v);
    }
}

extern "C" void kernel_launch(void* const* d_in, const int* in_sizes, int n_in,
                              void* d_out, int out_size, void* d_ws, size_t ws_size,
                              hipStream_t stream) {
    const float* x    = (const float*)d_in[0];
    const int*   esrc = (const int*)d_in[1];
    const int*   edst = (const int*)d_in[2];
    const float* ew   = (const float*)d_in[3];
    float*       out  = (float*)d_out;
    float*       buf  = (float*)d_ws;

    const int num_nodes = in_sizes[0] / DIM;
    const int num_edges = in_sizes[1];
    const size_t nbytes = (size_t)num_nodes * DIM * sizeof(float);

    const int block = 256;            // 4 waves/block
    const int grid  = 2048;           // 8192 waves grid-stride

    // layer 1: x -> out
    hipMemsetAsync(out, 0, nbytes, stream);
    spmm_scatter<<<grid, block, 0, stream>>>(x, esrc, edst, ew, out, num_edges);

    // layer 2: out -> buf
    hipMemsetAsync(buf, 0, nbytes, stream);
    spmm_scatter<<<grid, block, 0, stream>>>(out, esrc, edst, ew, buf, num_edges);

    // layer 3: buf -> out
    hipMemsetAsync(out, 0, nbytes, stream);
    spmm_scatter<<<grid, block, 0, stream>>>(buf, esrc, edst, ew, out, num_edges);
}

// Round 7
// 705.457 us; speedup vs baseline: 1.5586x; 1.5586x over previous
//
#include <hip/hip_runtime.h>

#define DIM 64
#define TPB 256
#define SCAN_ELEMS 1024   // elements per scan block (256 thr x 4/thread)

// ---------------- fallback: atomic scatter (round-0, proven) ----------------
__global__ void spmm_scatter(const float* __restrict__ xin,
                             const int* __restrict__ esrc,
                             const int* __restrict__ edst,
                             const float* __restrict__ ew,
                             float* __restrict__ xout,
                             int num_edges) {
    const int lane   = threadIdx.x & 63;
    const int wave   = (int)((blockIdx.x * blockDim.x + threadIdx.x) >> 6);
    const int nwaves = (int)((gridDim.x * blockDim.x) >> 6);
    for (int e = wave; e < num_edges; e += nwaves) {
        const int   s = esrc[e];
        const int   d = edst[e];
        const float w = ew[e];
        atomicAdd(&xout[(size_t)d * DIM + lane], w * xin[(size_t)s * DIM + lane]);
    }
}

// ---------------- CSR build ----------------
__global__ void hist_kernel(const int* __restrict__ edst, int* __restrict__ cnt, int E) {
    int e = blockIdx.x * blockDim.x + threadIdx.x;
    if (e < E) atomicAdd(&cnt[edst[e]], 1);
}

__global__ void scan_blocksum(const int* __restrict__ cnt, int* __restrict__ bsum, int n) {
    __shared__ int sd[TPB];
    const int base = blockIdx.x * SCAN_ELEMS;
    const int t = threadIdx.x;
    int s = 0;
    #pragma unroll
    for (int i = 0; i < 4; ++i) {
        int idx = base + t + i * TPB;
        if (idx < n) s += cnt[idx];
    }
    sd[t] = s; __syncthreads();
    for (int off = TPB / 2; off > 0; off >>= 1) {
        if (t < off) sd[t] += sd[t + off];
        __syncthreads();
    }
    if (t == 0) bsum[blockIdx.x] = sd[0];
}

__global__ void scan_bsums(int* __restrict__ bsum, int nb, int* __restrict__ row_ptr, int N) {
    __shared__ int sd[1024];
    const int t = threadIdx.x;
    const int orig = (t < nb) ? bsum[t] : 0;
    sd[t] = orig; __syncthreads();
    for (int off = 1; off < 1024; off <<= 1) {
        int v = (t >= off) ? sd[t - off] : 0;
        __syncthreads();
        sd[t] += v;
        __syncthreads();
    }
    if (t < nb) bsum[t] = sd[t] - orig;            // exclusive block offset
    if (t == nb - 1) row_ptr[N] = sd[t];           // grand total = E
}

__global__ void scan_final(const int* __restrict__ cnt, const int* __restrict__ bsum,
                           int* __restrict__ row_ptr, int* __restrict__ cursor, int n) {
    __shared__ int sd[TPB];
    const int base = blockIdx.x * SCAN_ELEMS;
    const int t = threadIdx.x;
    int v[4];
    int tsum = 0;
    #pragma unroll
    for (int i = 0; i < 4; ++i) {
        int idx = base + t * 4 + i;
        v[i] = (idx < n) ? cnt[idx] : 0;
        tsum += v[i];
    }
    sd[t] = tsum; __syncthreads();
    for (int off = 1; off < TPB; off <<= 1) {
        int u = (t >= off) ? sd[t - off] : 0;
        __syncthreads();
        sd[t] += u;
        __syncthreads();
    }
    const int excl = sd[t] - tsum;                 // exclusive within block
    int running = bsum[blockIdx.x] + excl;
    #pragma unroll
    for (int i = 0; i < 4; ++i) {
        int idx = base + t * 4 + i;
        if (idx < n) {
            row_ptr[idx] = running;
            cursor[idx]  = running;
            running += v[i];
        }
    }
}

__global__ void fill_kernel(const int* __restrict__ esrc, const int* __restrict__ edst,
                            const float* __restrict__ ew, int* __restrict__ cursor,
                            int2* __restrict__ entries, int E) {
    int e = blockIdx.x * blockDim.x + threadIdx.x;
    if (e < E) {
        int d = edst[e];
        int pos = atomicAdd(&cursor[d], 1);
        int2 en;
        en.x = esrc[e];
        en.y = __float_as_int(ew[e]);
        entries[pos] = en;
    }
}

// ---------------- pull-mode SpMM: one wave per dst node, no atomics ----------------
__global__ void spmm_pull(const float* __restrict__ xin,
                          const int2* __restrict__ entries,
                          const int* __restrict__ row_ptr,
                          float* __restrict__ xout,
                          int num_nodes) {
    const int lane = threadIdx.x & 63;
    const int wave = (int)((blockIdx.x * blockDim.x + threadIdx.x) >> 6);
    if (wave >= num_nodes) return;
    const int beg = row_ptr[wave];
    const int end = row_ptr[wave + 1];
    float acc = 0.f;
    for (int e = beg; e < end; ++e) {
        int2 en = entries[e];                       // wave-uniform 8B broadcast
        acc = fmaf(__int_as_float(en.y), xin[(size_t)en.x * DIM + lane], acc);
    }
    xout[(size_t)wave * DIM + lane] = acc;          // coalesced streaming store
}

extern "C" void kernel_launch(void* const* d_in, const int* in_sizes, int n_in,
                              void* d_out, int out_size, void* d_ws, size_t ws_size,
                              hipStream_t stream) {
    const float* x    = (const float*)d_in[0];
    const int*   esrc = (const int*)d_in[1];
    const int*   edst = (const int*)d_in[2];
    const float* ew   = (const float*)d_in[3];
    float*       out  = (float*)d_out;

    const int N = in_sizes[0] / DIM;
    const int E = in_sizes[1];
    const size_t xbytes = (size_t)N * DIM * sizeof(float);

    // ws layout (256B-aligned): entries | row_ptr | cursor | pingpong
    const size_t entries_sz  = (size_t)E * 8;
    const size_t rowptr_off  = (entries_sz + 255) & ~(size_t)255;
    const size_t rowptr_sz   = ((size_t)(N + 1) * 4 + 255) & ~(size_t)255;
    const size_t cursor_off  = rowptr_off + rowptr_sz;
    const size_t cursor_sz   = ((size_t)N * 4 + 255) & ~(size_t)255;
    const size_t ping_off    = cursor_off + cursor_sz;
    const size_t needed      = ping_off + xbytes;

    if (ws_size < needed) {
        // fallback: proven atomic-scatter path (needs only xbytes of ws)
        float* buf = (float*)d_ws;
        const int grid = 2048;
        hipMemsetAsync(out, 0, xbytes, stream);
        spmm_scatter<<<grid, TPB, 0, stream>>>(x, esrc, edst, ew, out, E);
        hipMemsetAsync(buf, 0, xbytes, stream);
        spmm_scatter<<<grid, TPB, 0, stream>>>(out, esrc, edst, ew, buf, E);
        hipMemsetAsync(out, 0, xbytes, stream);
        spmm_scatter<<<grid, TPB, 0, stream>>>(buf, esrc, edst, ew, out, E);
        return;
    }

    char* ws = (char*)d_ws;
    int2*  entries = (int2*)ws;
    int*   row_ptr = (int*)(ws + rowptr_off);
    int*   cursor  = (int*)(ws + cursor_off);
    float* buf     = (float*)(ws + ping_off);

    // ---- build CSR (by dst), once per call ----
    hipMemsetAsync(cursor, 0, (size_t)N * 4, stream);
    const int gE = (E + TPB - 1) / TPB;
    hist_kernel<<<gE, TPB, 0, stream>>>(edst, cursor, E);

    int* bsum = (int*)entries;                      // entries region unused until fill
    const int nb = (N + SCAN_ELEMS - 1) / SCAN_ELEMS;
    scan_blocksum<<<nb, TPB, 0, stream>>>(cursor, bsum, N);
    scan_bsums<<<1, 1024, 0, stream>>>(bsum, nb, row_ptr, N);
    scan_final<<<nb, TPB, 0, stream>>>(cursor, bsum, row_ptr, cursor, N);

    fill_kernel<<<gE, TPB, 0, stream>>>(esrc, edst, ew, cursor, entries, E);

    // ---- 3 pull-mode layers: x -> out -> buf -> out ----
    const int gN = ((size_t)N * 64 + TPB - 1) / TPB;   // one wave per node
    spmm_pull<<<gN, TPB, 0, stream>>>(x,   entries, row_ptr, out, N);
    spmm_pull<<<gN, TPB, 0, stream>>>(out, entries, row_ptr, buf, N);
    spmm_pull<<<gN, TPB, 0, stream>>>(buf, entries, row_ptr, out, N);
}

// Round 9
// 476.596 us; speedup vs baseline: 2.3071x; 1.4802x over previous
//
#include <hip/hip_runtime.h>

#define DIM 64
#define TPB 256
#define SCAN_ELEMS 1024   // elements per scan block (256 thr x 4/thread)

// ---------------- fallback: atomic scatter (round-0, proven) ----------------
__global__ void spmm_scatter(const float* __restrict__ xin,
                             const int* __restrict__ esrc,
                             const int* __restrict__ edst,
                             const float* __restrict__ ew,
                             float* __restrict__ xout,
                             int num_edges) {
    const int lane   = threadIdx.x & 63;
    const int wave   = (int)((blockIdx.x * blockDim.x + threadIdx.x) >> 6);
    const int nwaves = (int)((gridDim.x * blockDim.x) >> 6);
    for (int e = wave; e < num_edges; e += nwaves) {
        const int   s = esrc[e];
        const int   d = edst[e];
        const float w = ew[e];
        atomicAdd(&xout[(size_t)d * DIM + lane], w * xin[(size_t)s * DIM + lane]);
    }
}

// ---------------- CSR build ----------------
__global__ void hist_kernel(const int* __restrict__ edst, int* __restrict__ cnt, int E) {
    int e = blockIdx.x * blockDim.x + threadIdx.x;
    if (e < E) atomicAdd(&cnt[edst[e]], 1);
}

__global__ void scan_blocksum(const int* __restrict__ cnt, int* __restrict__ bsum, int n) {
    __shared__ int sd[TPB];
    const int base = blockIdx.x * SCAN_ELEMS;
    const int t = threadIdx.x;
    int s = 0;
    #pragma unroll
    for (int i = 0; i < 4; ++i) {
        int idx = base + t + i * TPB;
        if (idx < n) s += cnt[idx];
    }
    sd[t] = s; __syncthreads();
    for (int off = TPB / 2; off > 0; off >>= 1) {
        if (t < off) sd[t] += sd[t + off];
        __syncthreads();
    }
    if (t == 0) bsum[blockIdx.x] = sd[0];
}

__global__ void scan_bsums(int* __restrict__ bsum, int nb, int* __restrict__ row_ptr, int N) {
    __shared__ int sd[1024];
    const int t = threadIdx.x;
    const int orig = (t < nb) ? bsum[t] : 0;
    sd[t] = orig; __syncthreads();
    for (int off = 1; off < 1024; off <<= 1) {
        int v = (t >= off) ? sd[t - off] : 0;
        __syncthreads();
        sd[t] += v;
        __syncthreads();
    }
    if (t < nb) bsum[t] = sd[t] - orig;            // exclusive block offset
    if (t == nb - 1) row_ptr[N] = sd[t];           // grand total = E
}

__global__ void scan_final(const int* __restrict__ cnt, const int* __restrict__ bsum,
                           int* __restrict__ row_ptr, int* __restrict__ cursor, int n) {
    __shared__ int sd[TPB];
    const int base = blockIdx.x * SCAN_ELEMS;
    const int t = threadIdx.x;
    int v[4];
    int tsum = 0;
    #pragma unroll
    for (int i = 0; i < 4; ++i) {
        int idx = base + t * 4 + i;
        v[i] = (idx < n) ? cnt[idx] : 0;
        tsum += v[i];
    }
    sd[t] = tsum; __syncthreads();
    for (int off = 1; off < TPB; off <<= 1) {
        int u = (t >= off) ? sd[t - off] : 0;
        __syncthreads();
        sd[t] += u;
        __syncthreads();
    }
    const int excl = sd[t] - tsum;                 // exclusive within block
    int running = bsum[blockIdx.x] + excl;
    #pragma unroll
    for (int i = 0; i < 4; ++i) {
        int idx = base + t * 4 + i;
        if (idx < n) {
            row_ptr[idx] = running;
            cursor[idx]  = running;
            running += v[i];
        }
    }
}

__global__ void fill_kernel(const int* __restrict__ esrc, const int* __restrict__ edst,
                            const float* __restrict__ ew, int* __restrict__ cursor,
                            int2* __restrict__ entries, int E) {
    int e = blockIdx.x * blockDim.x + threadIdx.x;
    if (e < E) {
        int d = edst[e];
        int pos = atomicAdd(&cursor[d], 1);
        int2 en;
        en.x = esrc[e];
        en.y = __float_as_int(ew[e]);
        entries[pos] = en;
    }
}

// ---------------- pull-mode SpMM with 4-way ILP ----------------
// One wave per dst node; lane l owns dim l. Edge loop unrolled x4 with 4
// independent accumulators so 4 gathers are in flight per chain step.
__global__ void spmm_pull(const float* __restrict__ xin,
                          const int2* __restrict__ entries,
                          const int* __restrict__ row_ptr,
                          float* __restrict__ xout,
                          int num_nodes) {
    const int lane = threadIdx.x & 63;
    const int wave = (int)((blockIdx.x * blockDim.x + threadIdx.x) >> 6);
    if (wave >= num_nodes) return;
    const int beg = row_ptr[wave];
    const int end = row_ptr[wave + 1];

    float a0 = 0.f, a1 = 0.f, a2 = 0.f, a3 = 0.f;
    int e = beg;
    for (; e + 4 <= end; e += 4) {
        const int2 e0 = entries[e];
        const int2 e1 = entries[e + 1];
        const int2 e2 = entries[e + 2];
        const int2 e3 = entries[e + 3];
        const float x0 = xin[(size_t)e0.x * DIM + lane];
        const float x1 = xin[(size_t)e1.x * DIM + lane];
        const float x2 = xin[(size_t)e2.x * DIM + lane];
        const float x3 = xin[(size_t)e3.x * DIM + lane];
        a0 = fmaf(__int_as_float(e0.y), x0, a0);
        a1 = fmaf(__int_as_float(e1.y), x1, a1);
        a2 = fmaf(__int_as_float(e2.y), x2, a2);
        a3 = fmaf(__int_as_float(e3.y), x3, a3);
    }
    for (; e < end; ++e) {
        const int2 en = entries[e];
        a0 = fmaf(__int_as_float(en.y), xin[(size_t)en.x * DIM + lane], a0);
    }
    xout[(size_t)wave * DIM + lane] = (a0 + a1) + (a2 + a3);
}

extern "C" void kernel_launch(void* const* d_in, const int* in_sizes, int n_in,
                              void* d_out, int out_size, void* d_ws, size_t ws_size,
                              hipStream_t stream) {
    const float* x    = (const float*)d_in[0];
    const int*   esrc = (const int*)d_in[1];
    const int*   edst = (const int*)d_in[2];
    const float* ew   = (const float*)d_in[3];
    float*       out  = (float*)d_out;

    const int N = in_sizes[0] / DIM;
    const int E = in_sizes[1];
    const size_t xbytes = (size_t)N * DIM * sizeof(float);

    // ws layout (256B-aligned): entries | row_ptr | cursor | pingpong
    const size_t entries_sz  = (size_t)E * 8;
    const size_t rowptr_off  = (entries_sz + 255) & ~(size_t)255;
    const size_t rowptr_sz   = ((size_t)(N + 1) * 4 + 255) & ~(size_t)255;
    const size_t cursor_off  = rowptr_off + rowptr_sz;
    const size_t cursor_sz   = ((size_t)N * 4 + 255) & ~(size_t)255;
    const size_t ping_off    = cursor_off + cursor_sz;
    const size_t needed      = ping_off + xbytes;

    if (ws_size < needed) {
        // fallback: proven atomic-scatter path (needs only xbytes of ws)
        float* buf = (float*)d_ws;
        const int grid = 2048;
        hipMemsetAsync(out, 0, xbytes, stream);
        spmm_scatter<<<grid, TPB, 0, stream>>>(x, esrc, edst, ew, out, E);
        hipMemsetAsync(buf, 0, xbytes, stream);
        spmm_scatter<<<grid, TPB, 0, stream>>>(out, esrc, edst, ew, buf, E);
        hipMemsetAsync(out, 0, xbytes, stream);
        spmm_scatter<<<grid, TPB, 0, stream>>>(buf, esrc, edst, ew, out, E);
        return;
    }

    char* ws = (char*)d_ws;
    int2*  entries = (int2*)ws;
    int*   row_ptr = (int*)(ws + rowptr_off);
    int*   cursor  = (int*)(ws + cursor_off);
    float* buf     = (float*)(ws + ping_off);

    // ---- build CSR (by dst), once per call ----
    hipMemsetAsync(cursor, 0, (size_t)N * 4, stream);
    const int gE = (E + TPB - 1) / TPB;
    hist_kernel<<<gE, TPB, 0, stream>>>(edst, cursor, E);

    int* bsum = (int*)entries;                      // entries region unused until fill
    const int nb = (N + SCAN_ELEMS - 1) / SCAN_ELEMS;
    scan_blocksum<<<nb, TPB, 0, stream>>>(cursor, bsum, N);
    scan_bsums<<<1, 1024, 0, stream>>>(bsum, nb, row_ptr, N);
    scan_final<<<nb, TPB, 0, stream>>>(cursor, bsum, row_ptr, cursor, N);

    fill_kernel<<<gE, TPB, 0, stream>>>(esrc, edst, ew, cursor, entries, E);

    // ---- 3 pull-mode layers: x -> out -> buf -> out ----
    const int gN = ((size_t)N * 64 + TPB - 1) / TPB;   // one wave per node
    spmm_pull<<<gN, TPB, 0, stream>>>(x,   entries, row_ptr, out, N);
    spmm_pull<<<gN, TPB, 0, stream>>>(out, entries, row_ptr, buf, N);
    spmm_pull<<<gN, TPB, 0, stream>>>(buf, entries, row_ptr, out, N);
}

// Round 11
// 464.618 us; speedup vs baseline: 2.3665x; 1.0258x over previous
//
#include <hip/hip_runtime.h>

#define DIM 64
#define TPB 256
#define SCAN_ELEMS 1024   // elements per scan block (256 thr x 4/thread)

// ---------------- fallback: atomic scatter (round-0, proven) ----------------
__global__ void spmm_scatter(const float* __restrict__ xin,
                             const int* __restrict__ esrc,
                             const int* __restrict__ edst,
                             const float* __restrict__ ew,
                             float* __restrict__ xout,
                             int num_edges) {
    const int lane   = threadIdx.x & 63;
    const int wave   = (int)((blockIdx.x * blockDim.x + threadIdx.x) >> 6);
    const int nwaves = (int)((gridDim.x * blockDim.x) >> 6);
    for (int e = wave; e < num_edges; e += nwaves) {
        const int   s = esrc[e];
        const int   d = edst[e];
        const float w = ew[e];
        atomicAdd(&xout[(size_t)d * DIM + lane], w * xin[(size_t)s * DIM + lane]);
    }
}

// ---------------- CSR build ----------------
__global__ void hist_kernel(const int* __restrict__ edst, int* __restrict__ cnt, int E) {
    int e = blockIdx.x * blockDim.x + threadIdx.x;
    if (e < E) atomicAdd(&cnt[edst[e]], 1);
}

__global__ void scan_blocksum(const int* __restrict__ cnt, int* __restrict__ bsum, int n) {
    __shared__ int sd[TPB];
    const int base = blockIdx.x * SCAN_ELEMS;
    const int t = threadIdx.x;
    int s = 0;
    #pragma unroll
    for (int i = 0; i < 4; ++i) {
        int idx = base + t + i * TPB;
        if (idx < n) s += cnt[idx];
    }
    sd[t] = s; __syncthreads();
    for (int off = TPB / 2; off > 0; off >>= 1) {
        if (t < off) sd[t] += sd[t + off];
        __syncthreads();
    }
    if (t == 0) bsum[blockIdx.x] = sd[0];
}

__global__ void scan_bsums(int* __restrict__ bsum, int nb, int* __restrict__ row_ptr, int N) {
    __shared__ int sd[1024];
    const int t = threadIdx.x;
    const int orig = (t < nb) ? bsum[t] : 0;
    sd[t] = orig; __syncthreads();
    for (int off = 1; off < 1024; off <<= 1) {
        int v = (t >= off) ? sd[t - off] : 0;
        __syncthreads();
        sd[t] += v;
        __syncthreads();
    }
    if (t < nb) bsum[t] = sd[t] - orig;            // exclusive block offset
    if (t == nb - 1) row_ptr[N] = sd[t];           // grand total = E
}

__global__ void scan_final(const int* __restrict__ cnt, const int* __restrict__ bsum,
                           int* __restrict__ row_ptr, int* __restrict__ cursor, int n) {
    __shared__ int sd[TPB];
    const int base = blockIdx.x * SCAN_ELEMS;
    const int t = threadIdx.x;
    int v[4];
    int tsum = 0;
    #pragma unroll
    for (int i = 0; i < 4; ++i) {
        int idx = base + t * 4 + i;
        v[i] = (idx < n) ? cnt[idx] : 0;
        tsum += v[i];
    }
    sd[t] = tsum; __syncthreads();
    for (int off = 1; off < TPB; off <<= 1) {
        int u = (t >= off) ? sd[t - off] : 0;
        __syncthreads();
        sd[t] += u;
        __syncthreads();
    }
    const int excl = sd[t] - tsum;                 // exclusive within block
    int running = bsum[blockIdx.x] + excl;
    #pragma unroll
    for (int i = 0; i < 4; ++i) {
        int idx = base + t * 4 + i;
        if (idx < n) {
            row_ptr[idx] = running;
            cursor[idx]  = running;
            running += v[i];
        }
    }
}

// Non-temporal scatter store: avoid L2 write-allocate + cross-XCD line
// ping-pong on random 8B writes (round-9: WRITE_SIZE 100MB for a 12.8MB array).
// Packed as uint64_t: __builtin_nontemporal_store needs a scalar type (int2 fails).
__global__ void fill_kernel(const int* __restrict__ esrc, const int* __restrict__ edst,
                            const float* __restrict__ ew, int* __restrict__ cursor,
                            int2* __restrict__ entries, int E) {
    int e = blockIdx.x * blockDim.x + threadIdx.x;
    if (e < E) {
        int d = edst[e];
        int pos = atomicAdd(&cursor[d], 1);
        const unsigned long long packed =
            (unsigned long long)(unsigned int)esrc[e] |
            ((unsigned long long)(unsigned int)__float_as_uint(ew[e]) << 32);
        __builtin_nontemporal_store(packed, (unsigned long long*)&entries[pos]);
    }
}

// ---------------- pull-mode SpMM with 8-way ILP ----------------
// One wave per dst node; lane l owns dim l. Edge loop unrolled x8 with 8
// independent accumulators so 8 gathers are in flight per chain step.
__global__ void spmm_pull(const float* __restrict__ xin,
                          const int2* __restrict__ entries,
                          const int* __restrict__ row_ptr,
                          float* __restrict__ xout,
                          int num_nodes) {
    const int lane = threadIdx.x & 63;
    const int wave = (int)((blockIdx.x * blockDim.x + threadIdx.x) >> 6);
    if (wave >= num_nodes) return;
    const int beg = row_ptr[wave];
    const int end = row_ptr[wave + 1];

    float a0 = 0.f, a1 = 0.f, a2 = 0.f, a3 = 0.f;
    float a4 = 0.f, a5 = 0.f, a6 = 0.f, a7 = 0.f;
    int e = beg;
    for (; e + 8 <= end; e += 8) {
        const int2 e0 = entries[e];
        const int2 e1 = entries[e + 1];
        const int2 e2 = entries[e + 2];
        const int2 e3 = entries[e + 3];
        const int2 e4 = entries[e + 4];
        const int2 e5 = entries[e + 5];
        const int2 e6 = entries[e + 6];
        const int2 e7 = entries[e + 7];
        const float x0 = xin[(size_t)e0.x * DIM + lane];
        const float x1 = xin[(size_t)e1.x * DIM + lane];
        const float x2 = xin[(size_t)e2.x * DIM + lane];
        const float x3 = xin[(size_t)e3.x * DIM + lane];
        const float x4 = xin[(size_t)e4.x * DIM + lane];
        const float x5 = xin[(size_t)e5.x * DIM + lane];
        const float x6 = xin[(size_t)e6.x * DIM + lane];
        const float x7 = xin[(size_t)e7.x * DIM + lane];
        a0 = fmaf(__int_as_float(e0.y), x0, a0);
        a1 = fmaf(__int_as_float(e1.y), x1, a1);
        a2 = fmaf(__int_as_float(e2.y), x2, a2);
        a3 = fmaf(__int_as_float(e3.y), x3, a3);
        a4 = fmaf(__int_as_float(e4.y), x4, a4);
        a5 = fmaf(__int_as_float(e5.y), x5, a5);
        a6 = fmaf(__int_as_float(e6.y), x6, a6);
        a7 = fmaf(__int_as_float(e7.y), x7, a7);
    }
    for (; e + 4 <= end; e += 4) {
        const int2 e0 = entries[e];
        const int2 e1 = entries[e + 1];
        const int2 e2 = entries[e + 2];
        const int2 e3 = entries[e + 3];
        const float x0 = xin[(size_t)e0.x * DIM + lane];
        const float x1 = xin[(size_t)e1.x * DIM + lane];
        const float x2 = xin[(size_t)e2.x * DIM + lane];
        const float x3 = xin[(size_t)e3.x * DIM + lane];
        a0 = fmaf(__int_as_float(e0.y), x0, a0);
        a1 = fmaf(__int_as_float(e1.y), x1, a1);
        a2 = fmaf(__int_as_float(e2.y), x2, a2);
        a3 = fmaf(__int_as_float(e3.y), x3, a3);
    }
    for (; e < end; ++e) {
        const int2 en = entries[e];
        a0 = fmaf(__int_as_float(en.y), xin[(size_t)en.x * DIM + lane], a0);
    }
    xout[(size_t)wave * DIM + lane] =
        ((a0 + a1) + (a2 + a3)) + ((a4 + a5) + (a6 + a7));
}

extern "C" void kernel_launch(void* const* d_in, const int* in_sizes, int n_in,
                              void* d_out, int out_size, void* d_ws, size_t ws_size,
                              hipStream_t stream) {
    const float* x    = (const float*)d_in[0];
    const int*   esrc = (const int*)d_in[1];
    const int*   edst = (const int*)d_in[2];
    const float* ew   = (const float*)d_in[3];
    float*       out  = (float*)d_out;

    const int N = in_sizes[0] / DIM;
    const int E = in_sizes[1];
    const size_t xbytes = (size_t)N * DIM * sizeof(float);

    // ws layout (256B-aligned): entries | row_ptr | cursor | pingpong
    const size_t entries_sz  = (size_t)E * 8;
    const size_t rowptr_off  = (entries_sz + 255) & ~(size_t)255;
    const size_t rowptr_sz   = ((size_t)(N + 1) * 4 + 255) & ~(size_t)255;
    const size_t cursor_off  = rowptr_off + rowptr_sz;
    const size_t cursor_sz   = ((size_t)N * 4 + 255) & ~(size_t)255;
    const size_t ping_off    = cursor_off + cursor_sz;
    const size_t needed      = ping_off + xbytes;

    if (ws_size < needed) {
        // fallback: proven atomic-scatter path (needs only xbytes of ws)
        float* buf = (float*)d_ws;
        const int grid = 2048;
        hipMemsetAsync(out, 0, xbytes, stream);
        spmm_scatter<<<grid, TPB, 0, stream>>>(x, esrc, edst, ew, out, E);
        hipMemsetAsync(buf, 0, xbytes, stream);
        spmm_scatter<<<grid, TPB, 0, stream>>>(out, esrc, edst, ew, buf, E);
        hipMemsetAsync(out, 0, xbytes, stream);
        spmm_scatter<<<grid, TPB, 0, stream>>>(buf, esrc, edst, ew, out, E);
        return;
    }

    char* ws = (char*)d_ws;
    int2*  entries = (int2*)ws;
    int*   row_ptr = (int*)(ws + rowptr_off);
    int*   cursor  = (int*)(ws + cursor_off);
    float* buf     = (float*)(ws + ping_off);

    // ---- build CSR (by dst), once per call ----
    hipMemsetAsync(cursor, 0, (size_t)N * 4, stream);
    const int gE = (E + TPB - 1) / TPB;
    hist_kernel<<<gE, TPB, 0, stream>>>(edst, cursor, E);

    int* bsum = (int*)entries;                      // entries region unused until fill
    const int nb = (N + SCAN_ELEMS - 1) / SCAN_ELEMS;
    scan_blocksum<<<nb, TPB, 0, stream>>>(cursor, bsum, N);
    scan_bsums<<<1, 1024, 0, stream>>>(bsum, nb, row_ptr, N);
    scan_final<<<nb, TPB, 0, stream>>>(cursor, bsum, row_ptr, cursor, N);

    fill_kernel<<<gE, TPB, 0, stream>>>(esrc, edst, ew, cursor, entries, E);

    // ---- 3 pull-mode layers: x -> out -> buf -> out ----
    const int gN = ((size_t)N * 64 + TPB - 1) / TPB;   // one wave per node
    spmm_pull<<<gN, TPB, 0, stream>>>(x,   entries, row_ptr, out, N);
    spmm_pull<<<gN, TPB, 0, stream>>>(out, entries, row_ptr, buf, N);
    spmm_pull<<<gN, TPB, 0, stream>>>(buf, entries, row_ptr, out, N);
}

// Round 12
// 437.799 us; speedup vs baseline: 2.5115x; 1.0613x over previous
//
#include <hip/hip_runtime.h>

#define DIM 64
#define TPB 256
#define SCAN_ELEMS 1024   // elements per scan block (256 thr x 4/thread)

// ---------------- fallback: atomic scatter (round-0, proven) ----------------
__global__ void spmm_scatter(const float* __restrict__ xin,
                             const int* __restrict__ esrc,
                             const int* __restrict__ edst,
                             const float* __restrict__ ew,
                             float* __restrict__ xout,
                             int num_edges) {
    const int lane   = threadIdx.x & 63;
    const int wave   = (int)((blockIdx.x * blockDim.x + threadIdx.x) >> 6);
    const int nwaves = (int)((gridDim.x * blockDim.x) >> 6);
    for (int e = wave; e < num_edges; e += nwaves) {
        const int   s = esrc[e];
        const int   d = edst[e];
        const float w = ew[e];
        atomicAdd(&xout[(size_t)d * DIM + lane], w * xin[(size_t)s * DIM + lane]);
    }
}

// ---------------- CSR build ----------------
__global__ void hist_kernel(const int* __restrict__ edst, int* __restrict__ cnt, int E) {
    int e = blockIdx.x * blockDim.x + threadIdx.x;
    if (e < E) atomicAdd(&cnt[edst[e]], 1);
}

__global__ void scan_blocksum(const int* __restrict__ cnt, int* __restrict__ bsum, int n) {
    __shared__ int sd[TPB];
    const int base = blockIdx.x * SCAN_ELEMS;
    const int t = threadIdx.x;
    int s = 0;
    #pragma unroll
    for (int i = 0; i < 4; ++i) {
        int idx = base + t + i * TPB;
        if (idx < n) s += cnt[idx];
    }
    sd[t] = s; __syncthreads();
    for (int off = TPB / 2; off > 0; off >>= 1) {
        if (t < off) sd[t] += sd[t + off];
        __syncthreads();
    }
    if (t == 0) bsum[blockIdx.x] = sd[0];
}

__global__ void scan_bsums(int* __restrict__ bsum, int nb, int* __restrict__ row_ptr, int N) {
    __shared__ int sd[1024];
    const int t = threadIdx.x;
    const int orig = (t < nb) ? bsum[t] : 0;
    sd[t] = orig; __syncthreads();
    for (int off = 1; off < 1024; off <<= 1) {
        int v = (t >= off) ? sd[t - off] : 0;
        __syncthreads();
        sd[t] += v;
        __syncthreads();
    }
    if (t < nb) bsum[t] = sd[t] - orig;            // exclusive block offset
    if (t == nb - 1) row_ptr[N] = sd[t];           // grand total = E
}

__global__ void scan_final(const int* __restrict__ cnt, const int* __restrict__ bsum,
                           int* __restrict__ row_ptr, int* __restrict__ cursor, int n) {
    __shared__ int sd[TPB];
    const int base = blockIdx.x * SCAN_ELEMS;
    const int t = threadIdx.x;
    int v[4];
    int tsum = 0;
    #pragma unroll
    for (int i = 0; i < 4; ++i) {
        int idx = base + t * 4 + i;
        v[i] = (idx < n) ? cnt[idx] : 0;
        tsum += v[i];
    }
    sd[t] = tsum; __syncthreads();
    for (int off = 1; off < TPB; off <<= 1) {
        int u = (t >= off) ? sd[t - off] : 0;
        __syncthreads();
        sd[t] += u;
        __syncthreads();
    }
    const int excl = sd[t] - tsum;                 // exclusive within block
    int running = bsum[blockIdx.x] + excl;
    #pragma unroll
    for (int i = 0; i < 4; ++i) {
        int idx = base + t * 4 + i;
        if (idx < n) {
            row_ptr[idx] = running;
            cursor[idx]  = running;
            running += v[i];
        }
    }
}

// Plain int2 scatter store (round-11 measured: nt-store is a no-op here;
// random 8B scatters dirty full 64B lines regardless -> WRITE_SIZE ~100MB).
__global__ void fill_kernel(const int* __restrict__ esrc, const int* __restrict__ edst,
                            const float* __restrict__ ew, int* __restrict__ cursor,
                            int2* __restrict__ entries, int E) {
    int e = blockIdx.x * blockDim.x + threadIdx.x;
    if (e < E) {
        int d = edst[e];
        int pos = atomicAdd(&cursor[d], 1);
        int2 en;
        en.x = esrc[e];
        en.y = __float_as_int(ew[e]);
        entries[pos] = en;
    }
}

// ---------------- pull-mode SpMM: 4 rows/wave x 16 lanes x float4 ----------------
// Lane group g = lane>>4 owns node 4*wave+g; lane c = lane&15 holds dims 4c..4c+3.
// Unroll-4 per row -> 16 edges' gathers in flight per wave (4 load instrs),
// 4x fewer loop iterations than 1-row/wave, same 256B/row coalescing.
__global__ void spmm_pull4(const float4* __restrict__ xin4,
                           const int2* __restrict__ entries,
                           const int* __restrict__ row_ptr,
                           float4* __restrict__ xout4,
                           int num_nodes) {
    const int lane = threadIdx.x & 63;
    const int grp  = lane >> 4;            // row within wave (0..3)
    const int c    = lane & 15;            // float4 slot within row
    const int wave = (int)((blockIdx.x * blockDim.x + threadIdx.x) >> 6);
    const int node = wave * 4 + grp;
    if (node >= num_nodes) return;

    const int beg = row_ptr[node];
    const int end = row_ptr[node + 1];
    const int len = end - beg;

    float4 a0 = {0.f,0.f,0.f,0.f}, a1 = {0.f,0.f,0.f,0.f};
    float4 a2 = {0.f,0.f,0.f,0.f}, a3 = {0.f,0.f,0.f,0.f};

    int t = 0;
    for (; t + 4 <= len; t += 4) {
        const int2 e0 = entries[beg + t];
        const int2 e1 = entries[beg + t + 1];
        const int2 e2 = entries[beg + t + 2];
        const int2 e3 = entries[beg + t + 3];
        const float4 x0 = xin4[(size_t)e0.x * 16 + c];
        const float4 x1 = xin4[(size_t)e1.x * 16 + c];
        const float4 x2 = xin4[(size_t)e2.x * 16 + c];
        const float4 x3 = xin4[(size_t)e3.x * 16 + c];
        const float w0 = __int_as_float(e0.y);
        const float w1 = __int_as_float(e1.y);
        const float w2 = __int_as_float(e2.y);
        const float w3 = __int_as_float(e3.y);
        a0.x = fmaf(w0, x0.x, a0.x); a0.y = fmaf(w0, x0.y, a0.y);
        a0.z = fmaf(w0, x0.z, a0.z); a0.w = fmaf(w0, x0.w, a0.w);
        a1.x = fmaf(w1, x1.x, a1.x); a1.y = fmaf(w1, x1.y, a1.y);
        a1.z = fmaf(w1, x1.z, a1.z); a1.w = fmaf(w1, x1.w, a1.w);
        a2.x = fmaf(w2, x2.x, a2.x); a2.y = fmaf(w2, x2.y, a2.y);
        a2.z = fmaf(w2, x2.z, a2.z); a2.w = fmaf(w2, x2.w, a2.w);
        a3.x = fmaf(w3, x3.x, a3.x); a3.y = fmaf(w3, x3.y, a3.y);
        a3.z = fmaf(w3, x3.z, a3.z); a3.w = fmaf(w3, x3.w, a3.w);
    }
    for (; t < len; ++t) {
        const int2 en = entries[beg + t];
        const float4 xv = xin4[(size_t)en.x * 16 + c];
        const float w = __int_as_float(en.y);
        a0.x = fmaf(w, xv.x, a0.x); a0.y = fmaf(w, xv.y, a0.y);
        a0.z = fmaf(w, xv.z, a0.z); a0.w = fmaf(w, xv.w, a0.w);
    }
    float4 r;
    r.x = (a0.x + a1.x) + (a2.x + a3.x);
    r.y = (a0.y + a1.y) + (a2.y + a3.y);
    r.z = (a0.z + a1.z) + (a2.z + a3.z);
    r.w = (a0.w + a1.w) + (a2.w + a3.w);
    xout4[(size_t)node * 16 + c] = r;      // 16 lanes x 16B = 256B/row coalesced
}

extern "C" void kernel_launch(void* const* d_in, const int* in_sizes, int n_in,
                              void* d_out, int out_size, void* d_ws, size_t ws_size,
                              hipStream_t stream) {
    const float* x    = (const float*)d_in[0];
    const int*   esrc = (const int*)d_in[1];
    const int*   edst = (const int*)d_in[2];
    const float* ew   = (const float*)d_in[3];
    float*       out  = (float*)d_out;

    const int N = in_sizes[0] / DIM;
    const int E = in_sizes[1];
    const size_t xbytes = (size_t)N * DIM * sizeof(float);

    // ws layout (256B-aligned): entries | row_ptr | cursor | pingpong
    const size_t entries_sz  = (size_t)E * 8;
    const size_t rowptr_off  = (entries_sz + 255) & ~(size_t)255;
    const size_t rowptr_sz   = ((size_t)(N + 1) * 4 + 255) & ~(size_t)255;
    const size_t cursor_off  = rowptr_off + rowptr_sz;
    const size_t cursor_sz   = ((size_t)N * 4 + 255) & ~(size_t)255;
    const size_t ping_off    = cursor_off + cursor_sz;
    const size_t needed      = ping_off + xbytes;

    if (ws_size < needed) {
        // fallback: proven atomic-scatter path (needs only xbytes of ws)
        float* buf = (float*)d_ws;
        const int grid = 2048;
        hipMemsetAsync(out, 0, xbytes, stream);
        spmm_scatter<<<grid, TPB, 0, stream>>>(x, esrc, edst, ew, out, E);
        hipMemsetAsync(buf, 0, xbytes, stream);
        spmm_scatter<<<grid, TPB, 0, stream>>>(out, esrc, edst, ew, buf, E);
        hipMemsetAsync(out, 0, xbytes, stream);
        spmm_scatter<<<grid, TPB, 0, stream>>>(buf, esrc, edst, ew, out, E);
        return;
    }

    char* ws = (char*)d_ws;
    int2*  entries = (int2*)ws;
    int*   row_ptr = (int*)(ws + rowptr_off);
    int*   cursor  = (int*)(ws + cursor_off);
    float* buf     = (float*)(ws + ping_off);

    // ---- build CSR (by dst), once per call ----
    hipMemsetAsync(cursor, 0, (size_t)N * 4, stream);
    const int gE = (E + TPB - 1) / TPB;
    hist_kernel<<<gE, TPB, 0, stream>>>(edst, cursor, E);

    int* bsum = (int*)entries;                      // entries region unused until fill
    const int nb = (N + SCAN_ELEMS - 1) / SCAN_ELEMS;
    scan_blocksum<<<nb, TPB, 0, stream>>>(cursor, bsum, N);
    scan_bsums<<<1, 1024, 0, stream>>>(bsum, nb, row_ptr, N);
    scan_final<<<nb, TPB, 0, stream>>>(cursor, bsum, row_ptr, cursor, N);

    fill_kernel<<<gE, TPB, 0, stream>>>(esrc, edst, ew, cursor, entries, E);

    // ---- 3 pull-mode layers: x -> out -> buf -> out ----
    const int nwaves = (N + 3) / 4;                    // 4 nodes per wave
    const int gN = (nwaves * 64 + TPB - 1) / TPB;
    spmm_pull4<<<gN, TPB, 0, stream>>>((const float4*)x,   entries, row_ptr, (float4*)out, N);
    spmm_pull4<<<gN, TPB, 0, stream>>>((const float4*)out, entries, row_ptr, (float4*)buf, N);
    spmm_pull4<<<gN, TPB, 0, stream>>>((const float4*)buf, entries, row_ptr, (float4*)out, N);
}